// Round 9
// baseline (43.596 us; speedup 1.0000x reference)
//
#include <hip/hip_runtime.h>

// FourierFilter2D: out[b,h,w,f] = Re( sum_c x[b,h,w,c] * W[c,h,w,f] ) + b_re[f]
// B=8, H=64, W=64, C=64, F=64. Output: [B][H][W][F] float32, REAL part only.
//
// History: r6 LDS-broadcast 36.6us; r7 s_load 87us; r8 MFMA 42us. All shared
// the true limiter: 16 waves/CU (grid 1024x4) and latency-bound W streams
// (VALUBusy<=16%, occupancy 23-38%). This version attacks CONCURRENCY:
//  - 8192 waves (32/CU, 100% occupancy): each wave owns (hw, b-half of 4).
//  - No LDS, no barriers: x[b][hw][c..c+3] loaded as a same-address float4
//    (64 lanes at one address = one coalesced L1 transaction, broadcast).
//    x register-cached per c-quad; still read from HBM exactly once.
//  - W per-lane dword streams (lane=f, 256B/wave/instr). The two b-half
//    waves of one hw share a block, so the 2nd W read hits L1/L2 (L2 has
//    34.5 TB/s aggregate; extra on-chip traffic is free vs latency win).
// Budget: VALU ~3.4us, vmem issue ~3.4us, HBM replay ~75-90MB ~13-15us ->
// memory-bound ~15-20us (was 36.6).

typedef float f32x4 __attribute__((ext_vector_type(4)));

constexpr int B  = 8;
constexpr int C  = 64;
constexpr int F  = 64;
constexpr int HW  = 4096;
constexpr int HWC = HW * C;         // 262144
constexpr int HWF = HW * F;         // 262144

__global__ __launch_bounds__(256) void fourier_filter2d_kernel(
    const float* __restrict__ x_re, const float* __restrict__ x_im,
    const float* __restrict__ w_re, const float* __restrict__ w_im,
    const float* __restrict__ b_re,
    float* __restrict__ out)
{
    const int wid  = threadIdx.x >> 6;          // 0..3
    const int lane = threadIdx.x & 63;          // f
    const int hw   = blockIdx.x * 2 + (wid >> 1);   // 2 hw per block
    const int b0   = (wid & 1) * 4;                 // b-half: 0..3 or 4..7

    // Wave-uniform x row pointers (per-lane identical addresses -> L1 broadcast).
    const float* __restrict__ xr = x_re + (size_t)b0 * HWC + hw * C;
    const float* __restrict__ xi = x_im + (size_t)b0 * HWC + hw * C;

    // Lane `lane` owns filter f = lane. 64 lanes x 4B = 256B coalesced per instr.
    const float* __restrict__ wr = w_re + (size_t)hw * F + lane;
    const float* __restrict__ wi = w_im + (size_t)hw * F + lane;

    float acc[4];
    #pragma unroll
    for (int b = 0; b < 4; ++b) acc[b] = 0.0f;

    #pragma unroll 2
    for (int c4 = 0; c4 < C; c4 += 4) {
        // x: 8 same-address float4 loads (register cache for 4 c, 4 b, re+im).
        f32x4 xrv[4], xiv[4];
        #pragma unroll
        for (int b = 0; b < 4; ++b) {
            xrv[b] = *(const f32x4*)(xr + (size_t)b * HWC + c4);
            xiv[b] = *(const f32x4*)(xi + (size_t)b * HWC + c4);
        }
        // W: 8 per-lane dword streams (c-stride = 1MB).
        float wrv[4], wiv[4];
        #pragma unroll
        for (int j = 0; j < 4; ++j) {
            wrv[j] = wr[(size_t)(c4 + j) * HWF];
            wiv[j] = wi[(size_t)(c4 + j) * HWF];
        }
        // Re((xr + i*xi)*(wr + i*wi)) = xr*wr - xi*wi
        #pragma unroll
        for (int j = 0; j < 4; ++j) {
            #pragma unroll
            for (int b = 0; b < 4; ++b) {
                acc[b] = fmaf(xrv[b][j], wrv[j], fmaf(-xiv[b][j], wiv[j], acc[b]));
            }
        }
    }

    const float bias = b_re[lane];
    #pragma unroll
    for (int b = 0; b < 4; ++b)
        out[(size_t)(b0 + b) * HWF + hw * F + lane] = acc[b] + bias;
}

extern "C" void kernel_launch(void* const* d_in, const int* in_sizes, int n_in,
                              void* d_out, int out_size, void* d_ws, size_t ws_size,
                              hipStream_t stream) {
    const float* x_re = (const float*)d_in[0];
    const float* x_im = (const float*)d_in[1];
    const float* w_re = (const float*)d_in[2];
    const float* w_im = (const float*)d_in[3];
    const float* b_re = (const float*)d_in[4];
    float* out = (float*)d_out;

    const int blocks = HW / 2; // 2048 blocks x 4 waves = 8192 waves = 32/CU
    fourier_filter2d_kernel<<<blocks, 256, 0, stream>>>(
        x_re, x_im, w_re, w_im, b_re, out);
}

// Round 10
// 35.184 us; speedup vs baseline: 1.2391x; 1.2391x over previous
//
#include <hip/hip_runtime.h>

// FourierFilter2D: out[b,h,w,f] = Re( sum_c x[b,h,w,c] * W[c,h,w,f] ) + b_re[f]
// B=8, H=64, W=64, C=64, F=64. Output: [B][H][W][F] float32, REAL part only.
//
// Landscape (r6-r9): x-operand delivery mechanism dominates.
//   r6 LDS-broadcast 36.6us | r7 s_load 87us | r8 MFMA 42us | r9 vmem-bcast 43.6us
// r9 lesson: vmem instruction COUNT is a first-class cost (broadcast loads are
// not free); r6's LDS path has the fewest vmem instrs/wave (~140).
// This version = r6 + b-split concurrency:
//   - block = 4 waves = 2 hw x 2 b-halves; x staged once per block (8KB LDS)
//   - grid 2048 blocks -> 8192 waves = 32/CU (launch_bounds caps VGPR at 64)
//   - per-wave: 256 ds_read_b64 (half of r6), 128 W dword loads (2nd b-half
//     wave hits L1 since same block reads same W), 4 stores.

constexpr int B  = 8;
constexpr int C  = 64;
constexpr int F  = 64;
constexpr int HW  = 4096;
constexpr int HWC = HW * C;         // 262144
constexpr int HWF = HW * F;         // 262144

__global__ __launch_bounds__(256, 8) void fourier_filter2d_kernel(
    const float* __restrict__ x_re, const float* __restrict__ x_im,
    const float* __restrict__ w_re, const float* __restrict__ w_im,
    const float* __restrict__ b_re,
    float* __restrict__ out)
{
    __shared__ float2 xs[2][B][C];   // 8 KB: x for the block's 2 hw positions

    const int t = threadIdx.x;

    // ---- Stage x for 2 hw (1024 float2 elems, 4 per thread, c-coalesced).
    #pragma unroll
    for (int k = 0; k < 4; ++k) {
        const int e    = t + k * 256;
        const int hw_l = e >> 9;
        const int b    = (e >> 6) & 7;
        const int c    = e & 63;
        const int gi   = b * HWC + (blockIdx.x * 2 + hw_l) * C + c;
        xs[hw_l][b][c] = make_float2(x_re[gi], x_im[gi]);
    }
    __syncthreads();

    const int wid   = t >> 6;
    const int lane  = t & 63;
    const int hw_l  = wid >> 1;                 // which of the block's 2 hw
    const int b0    = (wid & 1) * 4;            // b-half: 0..3 or 4..7
    const int hw    = blockIdx.x * 2 + hw_l;

    // Lane owns filter f = lane. W loads: 64 lanes x 4B = 256B coalesced.
    const float* __restrict__ wr = w_re + (size_t)hw * F + lane;
    const float* __restrict__ wi = w_im + (size_t)hw * F + lane;

    float acc[4];
    #pragma unroll
    for (int b = 0; b < 4; ++b) acc[b] = 0.0f;

    #pragma unroll 8
    for (int c = 0; c < C; ++c) {
        const float wrv = wr[(size_t)c * HWF];
        const float wiv = wi[(size_t)c * HWF];
        #pragma unroll
        for (int b = 0; b < 4; ++b) {
            const float2 x = xs[hw_l][b0 + b][c];   // wave-uniform -> LDS broadcast
            // Re((xr + i*xi)*(wr + i*wi)) = xr*wr - xi*wi
            acc[b] = fmaf(x.x, wrv, fmaf(-x.y, wiv, acc[b]));
        }
    }

    const float bias = b_re[lane];
    #pragma unroll
    for (int b = 0; b < 4; ++b)
        out[(size_t)(b0 + b) * HWF + (size_t)hw * F + lane] = acc[b] + bias;
}

extern "C" void kernel_launch(void* const* d_in, const int* in_sizes, int n_in,
                              void* d_out, int out_size, void* d_ws, size_t ws_size,
                              hipStream_t stream) {
    const float* x_re = (const float*)d_in[0];
    const float* x_im = (const float*)d_in[1];
    const float* w_re = (const float*)d_in[2];
    const float* w_im = (const float*)d_in[3];
    const float* b_re = (const float*)d_in[4];
    float* out = (float*)d_out;

    const int blocks = HW / 2; // 2048 blocks x 4 waves = 8192 waves = 32/CU
    fourier_filter2d_kernel<<<blocks, 256, 0, stream>>>(
        x_re, x_im, w_re, w_im, b_re, out);
}

// Round 11
// 32.117 us; speedup vs baseline: 1.3574x; 1.0955x over previous
//
#include <hip/hip_runtime.h>

// FourierFilter2D: out[b,h,w,f] = Re( sum_c x[b,h,w,c] * W[c,h,w,f] ) + b_re[f]
// B=8, H=64, W=64, C=64, F=64. Output: [B][H][W][F] float32, REAL part only.
//
// r6-r10 landscape: ~35us wall independent of occupancy (38->74%), VALU 20%,
// HBM 19%, conflicts 0. Common factor: W streamed as 4B/lane dwords (256B per
// vmem instr). m13's 6.3TB/s uses 16B/lane. Hypothesis: per-instruction
// request overhead is the wall -> quadruple bytes/instr.
//
// Structure: block = 4 waves = 4 consecutive hw x all 8 b.
//   wave w owns c in [16w, 16w+16): W loads are dwordx4 (1KB/instr: 4hw x 64f),
//   lane l -> (hw_l = l>>4, f = (l&15)*4 + 0..3). Each W element loaded once.
//   x in LDS (float2, stride-5 pad, 16-lane-group broadcast reads).
//   Cross-wave c-reduction via LDS partials (aliased over xs, barrier-fenced).
//   Inner math in f32x2 ext-vectors -> v_pk_fma_f32.

typedef float f32x2 __attribute__((ext_vector_type(2)));
typedef float f32x4 __attribute__((ext_vector_type(4)));

constexpr int Bb = 8;
constexpr int C  = 64;
constexpr int F  = 64;
constexpr int HW  = 4096;
constexpr int HWC = HW * C;         // 262144
constexpr int HWF = HW * F;         // 262144

// LDS region, time-multiplexed:
//  phase A: xs   = f32x2[(b*64+c)*5 + hw_l]   -> 8*64*5*8B  = 20480 B
//  phase B: part = float[(w*64+lane)*34 + j]  -> 4*64*34*4B = 34816 B
constexpr int SMEM_BYTES = 34816;

__global__ __launch_bounds__(256, 4) void fourier_filter2d_kernel(
    const float* __restrict__ x_re, const float* __restrict__ x_im,
    const float* __restrict__ w_re, const float* __restrict__ w_im,
    const float* __restrict__ b_re,
    float* __restrict__ out)
{
    __shared__ __align__(16) char smem_raw[SMEM_BYTES];
    f32x2* xs   = (f32x2*)smem_raw;
    float* part = (float*)smem_raw;

    const int t    = threadIdx.x;
    const int wid  = t >> 6;
    const int lane = t & 63;
    const int hw0  = blockIdx.x * 4;

    // ---- Stage x for 4 hw (dwordx4 global loads, 2 chunks/thread).
    #pragma unroll
    for (int k = 0; k < 2; ++k) {
        const int chunk = t + k * 256;       // 512 chunks: b(8) x hw_l(4) x c4(16)
        const int b    = chunk >> 6;
        const int r    = chunk & 63;
        const int hw_l = r >> 4;
        const int c4   = (r & 15) * 4;
        const size_t g = (size_t)b * HWC + (size_t)(hw0 + hw_l) * C + c4;
        const f32x4 vr = *(const f32x4*)(x_re + g);
        const f32x4 vi = *(const f32x4*)(x_im + g);
        #pragma unroll
        for (int j = 0; j < 4; ++j)
            xs[(b * 64 + c4 + j) * 5 + hw_l] = (f32x2){vr[j], vi[j]};
    }
    __syncthreads();

    // ---- Compute: wave wid covers c in [wid*16, wid*16+16).
    const int hw_l = lane >> 4;          // this lane's hw within the block
    const int c_lo = wid * 16;

    f32x2 acc[Bb][2];
    #pragma unroll
    for (int b = 0; b < Bb; ++b) { acc[b][0] = (f32x2)0.f; acc[b][1] = (f32x2)0.f; }

    #pragma unroll 4
    for (int cc = 0; cc < 16; ++cc) {
        const int c = c_lo + cc;
        const size_t off = ((size_t)c * HW + hw0) * F + lane * 4;
        const f32x4 wr4 = *(const f32x4*)(w_re + off);   // 1KB/wave: 4hw x 64f
        const f32x4 wi4 = *(const f32x4*)(w_im + off);
        const f32x2 wlo = wr4.lo, whi = wr4.hi;
        const f32x2 ilo = wi4.lo, ihi = wi4.hi;
        #pragma unroll
        for (int b = 0; b < Bb; ++b) {
            const f32x2 xv = xs[(b * 64 + c) * 5 + hw_l];  // 4-addr broadcast
            // Re((xr+i*xi)*(wr+i*wi)) = xr*wr - xi*wi   (per f pair)
            acc[b][0] = (acc[b][0] + wlo * xv.x) - ilo * xv.y;
            acc[b][1] = (acc[b][1] + whi * xv.x) - ihi * xv.y;
        }
    }

    // ---- Cross-wave reduction: partials to LDS (aliases xs; barrier-fenced).
    __syncthreads();
    const int pbase = (wid * 64 + lane) * 34;
    #pragma unroll
    for (int b = 0; b < Bb; ++b) {
        *(f32x2*)&part[pbase + b * 4]     = acc[b][0];
        *(f32x2*)&part[pbase + b * 4 + 2] = acc[b][1];
    }
    __syncthreads();

    // ---- Phase 2: wave w2 = wid handles hw_l2 = wid; lanes cover f 0..63.
    const int f        = lane;
    const int lane_src = wid * 16 + (f >> 2);
    const int jo       = f & 3;
    const float bias   = b_re[f];

    #pragma unroll
    for (int b = 0; b < Bb; ++b) {
        float s = 0.f;
        #pragma unroll
        for (int wv = 0; wv < 4; ++wv)
            s += part[(wv * 64 + lane_src) * 34 + b * 4 + jo];
        out[(size_t)b * HWF + (size_t)(hw0 + wid) * F + f] = s + bias;
    }
}

extern "C" void kernel_launch(void* const* d_in, const int* in_sizes, int n_in,
                              void* d_out, int out_size, void* d_ws, size_t ws_size,
                              hipStream_t stream) {
    const float* x_re = (const float*)d_in[0];
    const float* x_im = (const float*)d_in[1];
    const float* w_re = (const float*)d_in[2];
    const float* w_im = (const float*)d_in[3];
    const float* b_re = (const float*)d_in[4];
    float* out = (float*)d_out;

    const int blocks = HW / 4; // 1024 blocks x 4 waves; W loads dwordx4
    fourier_filter2d_kernel<<<blocks, 256, 0, stream>>>(
        x_re, x_im, w_re, w_im, b_re, out);
}